// Round 5
// baseline (5018.668 us; speedup 1.0000x reference)
//
#include <hip/hip_runtime.h>
#include <math.h>

#define N 8
#define Q 900
#define D 256
#define HB 200
#define WB 200
#define L 6
#define NH 8
#define P 4
#define HD 32
#define FF 512
#define NCLS 10
#define ODIM 18
#define HW (HB*WB)
#define NQ (N*Q)
#define NQD (NQ*D)
#define QD (Q*D)
#define SCALE 0.17677669529663687f

// ---------------- generic tiled f32 GEMM:  C[M,Nc] = act(A[M,K] @ B[K,Nc] + bias) ----------------
// ACT: 0 = none, 1 = relu, 2 = det head (sigmoid on cols < NCLS)
#define TM 64
#define TN 64
#define TK 16

template <int ACT>
__global__ __launch_bounds__(256) void gemm_kernel(
    const float* __restrict__ A, const float* __restrict__ B,
    const float* __restrict__ bias, float* __restrict__ C,
    int M, int K, int Nc) {
  __shared__ float AsT[TK][TM + 4];
  __shared__ float Bs[TK][TN + 4];
  const int tid = threadIdx.x;
  const int tx = tid & 15, ty = tid >> 4;
  const int m0 = blockIdx.x * TM, n0 = blockIdx.y * TN;

  float c[4][4] = {};

  for (int kt = 0; kt < K; kt += TK) {
    {
      int r = tid >> 2;                  // 0..63
      int cb = (tid & 3) * 4;            // 0,4,8,12
      int gr = m0 + r;
      float4 av = make_float4(0.f, 0.f, 0.f, 0.f);
      if (gr < M) av = *(const float4*)(A + (size_t)gr * K + kt + cb);
      AsT[cb + 0][r] = av.x;
      AsT[cb + 1][r] = av.y;
      AsT[cb + 2][r] = av.z;
      AsT[cb + 3][r] = av.w;
    }
    {
      int r = tid >> 4;                  // 0..15
      int cb = (tid & 15) * 4;           // 0..60
#pragma unroll
      for (int u = 0; u < 4; ++u) {
        int gc = n0 + cb + u;
        Bs[r][cb + u] = (gc < Nc) ? B[(size_t)(kt + r) * Nc + gc] : 0.f;
      }
    }
    __syncthreads();
#pragma unroll
    for (int kk = 0; kk < TK; ++kk) {
      float4 av = *(const float4*)&AsT[kk][ty * 4];
      float4 bv = *(const float4*)&Bs[kk][tx * 4];
      c[0][0] += av.x * bv.x; c[0][1] += av.x * bv.y; c[0][2] += av.x * bv.z; c[0][3] += av.x * bv.w;
      c[1][0] += av.y * bv.x; c[1][1] += av.y * bv.y; c[1][2] += av.y * bv.z; c[1][3] += av.y * bv.w;
      c[2][0] += av.z * bv.x; c[2][1] += av.z * bv.y; c[2][2] += av.z * bv.z; c[2][3] += av.z * bv.w;
      c[3][0] += av.w * bv.x; c[3][1] += av.w * bv.y; c[3][2] += av.w * bv.z; c[3][3] += av.w * bv.w;
    }
    __syncthreads();
  }

#pragma unroll
  for (int i = 0; i < 4; ++i) {
    int row = m0 + ty * 4 + i;
    if (row >= M) continue;
#pragma unroll
    for (int j = 0; j < 4; ++j) {
      int col = n0 + tx * 4 + j;
      if (col >= Nc) continue;
      float v = c[i][j] + bias[col];
      if (ACT == 1) v = fmaxf(v, 0.f);
      if (ACT == 2 && col < NCLS) v = 1.f / (1.f + expf(-v));
      C[(size_t)row * Nc + col] = v;
    }
  }
}

// ---------------- MHA: one thread per query row, online softmax over 900 keys ----------------
__global__ __launch_bounds__(256) void attn_kernel(
    const float* __restrict__ qg, const float* __restrict__ kg,
    const float* __restrict__ vg, float* __restrict__ og) {
  const int n = blockIdx.z, h = blockIdx.y;
  const int r = blockIdx.x * 256 + threadIdx.x;
  const bool active = (r < Q);
  __shared__ float ks[64][36];
  __shared__ float vs[64][36];

  float qreg[HD];
  if (active) {
    const float* qp = qg + ((size_t)(n * Q + r) * D + h * HD);
#pragma unroll
    for (int d = 0; d < HD; d += 4) {
      float4 v = *(const float4*)(qp + d);
      qreg[d] = v.x; qreg[d + 1] = v.y; qreg[d + 2] = v.z; qreg[d + 3] = v.w;
    }
  }
  float m = -1e30f, l = 0.f;
  float acc[HD] = {};

  for (int kt = 0; kt < Q; kt += 64) {
    int nk = min(64, Q - kt);
    {
      int row = threadIdx.x >> 2;
      int cb = (threadIdx.x & 3) * 8;
      if (kt + row < Q) {
        const float* kp = kg + ((size_t)(n * Q + kt + row) * D + h * HD + cb);
        const float* vp = vg + ((size_t)(n * Q + kt + row) * D + h * HD + cb);
        *(float4*)&ks[row][cb] = *(const float4*)kp;
        *(float4*)&ks[row][cb + 4] = *(const float4*)(kp + 4);
        *(float4*)&vs[row][cb] = *(const float4*)vp;
        *(float4*)&vs[row][cb + 4] = *(const float4*)(vp + 4);
      }
    }
    __syncthreads();
    if (active) {
      for (int j = 0; j < nk; ++j) {
        float s = 0.f;
#pragma unroll
        for (int d = 0; d < HD; ++d) s += qreg[d] * ks[j][d];
        s *= SCALE;
        if (s > m) {
          float corr = expf(m - s);
          l *= corr;
#pragma unroll
          for (int d = 0; d < HD; ++d) acc[d] *= corr;
          m = s;
        }
        float p = expf(s - m);
        l += p;
#pragma unroll
        for (int d = 0; d < HD; ++d) acc[d] += p * vs[j][d];
      }
    }
    __syncthreads();
  }
  if (active) {
    float inv = 1.f / l;
    float* op = og + ((size_t)(n * Q + r) * D + h * HD);
#pragma unroll
    for (int d = 0; d < HD; ++d) op[d] = acc[d] * inv;
  }
}

// ---------------- LayerNorm of (A + B), one block per row ----------------
__global__ __launch_bounds__(256) void ln_add_kernel(
    const float* __restrict__ A, const float* __restrict__ Bp,
    const float* __restrict__ g, const float* __restrict__ b,
    float* __restrict__ out) {
  const int row = blockIdx.x;
  const int t = threadIdx.x;
  const size_t base = (size_t)row * D + t;
  float v = A[base] + Bp[base];
  __shared__ float red[256];
  red[t] = v;
  __syncthreads();
#pragma unroll
  for (int s = 128; s > 0; s >>= 1) {
    if (t < s) red[t] += red[t + s];
    __syncthreads();
  }
  float mean = red[0] * (1.f / D);
  __syncthreads();
  float dv = v - mean;
  red[t] = dv * dv;
  __syncthreads();
#pragma unroll
  for (int s = 128; s > 0; s >>= 1) {
    if (t < s) red[t] += red[t + s];
    __syncthreads();
  }
  float var = red[0] * (1.f / D);
  float inv_std = 1.0f / sqrtf(var + 1e-5f);
  out[base] = dv * inv_std * g[t] + b[t];
}

// ---------------- deformable attention, fully fused ----------------
__global__ __launch_bounds__(256) void deform_kernel(
    const float* __restrict__ bev, const float* __restrict__ x2,
    const float* __restrict__ offW, const float* __restrict__ offb,
    const float* __restrict__ awW, const float* __restrict__ awb,
    const float* __restrict__ dvW, const float* __restrict__ dvb,
    float* __restrict__ dtmp) {
  const int bq = blockIdx.x;  // n*Q + qi
  const int n = bq / Q, qi = bq - n * Q;
  const int t = threadIdx.x;

  __shared__ float x2s[D];
  __shared__ float logit_s[96];          // 64 off logits + 32 aw logits
  __shared__ float aw_s[NH * P];
  __shared__ int   idx_s[NH * P * 4];
  __shared__ float w_s[NH * P * 4];
  __shared__ float agg_s[NH][D + 4];

  x2s[t] = x2[(size_t)bq * D + t];
  __syncthreads();

  // ---- off / aw logits: 96 dot products of length 256 ----
  if (t < 96) {
    float acc;
    if (t < 64) {
      acc = offb[t];
      for (int dd = 0; dd < D; ++dd) acc += x2s[dd] * offW[(size_t)dd * 64 + t];
    } else {
      int j = t - 64;
      acc = awb[j];
      for (int dd = 0; dd < D; ++dd) acc += x2s[dd] * awW[(size_t)dd * 32 + j];
    }
    logit_s[t] = acc;
  }
  __syncthreads();

  // ---- corners & bilinear weights (t = h*P+p), aw softmax (t = h) ----
  if (t < NH * P) {
    // reference point: replicate XLA f32 linspace with reciprocal-multiply delta:
    // delta = f32(39999 * f32(1/899)) = 44.492767333984375 (down-rounded vs exact div)
    // tq = f32(qi * delta), round half-even.
    // Gives ir(484)=21534 (tq=21534.5), ir(553)=24604 (tq=24604.5); all other
    // indices match the correctly-rounded-division model.
    float tq = __fmul_rn((float)qi, 44.492767333984375f);
    int ir = (int)rintf(tq);
    float rx = (float)(ir % WB);
    float ry = (float)(ir / WB);
    float ox = logit_s[t * 2 + 0];
    float oy = logit_s[t * 2 + 1];
    float lx = fminf(fmaxf(rx + ox, 0.f), (float)(WB - 1));
    float ly = fminf(fmaxf(ry + oy, 0.f), (float)(HB - 1));
    float x0 = floorf(lx), y0 = floorf(ly);
    float x1 = fminf(x0 + 1.f, (float)(WB - 1));
    float y1 = fminf(y0 + 1.f, (float)(HB - 1));
    float wx = lx - x0, wy = ly - y0;
    int b4 = t * 4;
    idx_s[b4 + 0] = (int)y0 * WB + (int)x0; w_s[b4 + 0] = (1.f - wx) * (1.f - wy);
    idx_s[b4 + 1] = (int)y0 * WB + (int)x1; w_s[b4 + 1] = wx * (1.f - wy);
    idx_s[b4 + 2] = (int)y1 * WB + (int)x0; w_s[b4 + 2] = (1.f - wx) * wy;
    idx_s[b4 + 3] = (int)y1 * WB + (int)x1; w_s[b4 + 3] = wx * wy;
  }
  if (t < NH) {
    float l0 = logit_s[64 + t * P + 0], l1 = logit_s[64 + t * P + 1];
    float l2 = logit_s[64 + t * P + 2], l3 = logit_s[64 + t * P + 3];
    float mx = fmaxf(fmaxf(l0, l1), fmaxf(l2, l3));
    float e0 = expf(l0 - mx), e1 = expf(l1 - mx), e2 = expf(l2 - mx), e3 = expf(l3 - mx);
    float inv = 1.f / (e0 + e1 + e2 + e3);
    aw_s[t * P + 0] = e0 * inv; aw_s[t * P + 1] = e1 * inv;
    aw_s[t * P + 2] = e2 * inv; aw_s[t * P + 3] = e3 * inv;
  }
  __syncthreads();

  // ---- gather + blend: wave-pair handles heads {w, w+4}; lane handles 4 channels ----
  {
    const float* bevn = bev + (size_t)n * HW * D;
    const int w4 = t >> 6;        // 0..3
    const int lane = t & 63;      // 0..63
#pragma unroll
    for (int hh2 = 0; hh2 < 2; ++hh2) {
      const int h = w4 + hh2 * 4;
#pragma unroll
      for (int cc = 0; cc < 4; ++cc) {
        const int c = lane + cc * 64;
        float acc = 0.f;
#pragma unroll
        for (int p = 0; p < P; ++p) {
          const int e = h * P + p;
          const int b4 = e * 4;
          float s4 = w_s[b4 + 0] * bevn[(size_t)idx_s[b4 + 0] * D + c]
                   + w_s[b4 + 1] * bevn[(size_t)idx_s[b4 + 1] * D + c]
                   + w_s[b4 + 2] * bevn[(size_t)idx_s[b4 + 2] * D + c]
                   + w_s[b4 + 3] * bevn[(size_t)idx_s[b4 + 3] * D + c];
          acc += aw_s[e] * s4;
        }
        agg_s[h][c] = acc;
      }
    }
  }
  __syncthreads();

  // ---- per-head projection: out channel t = head t>>5 ----
  {
    const int h = t >> 5;
    float acc = dvb[t];
    const float* wcol = dvW + t;
    const float* ag = agg_s[h];
    for (int dd = 0; dd < D; ++dd) acc += ag[dd] * wcol[(size_t)dd * D];
    dtmp[(size_t)bq * D + t] = acc;
  }
}

// ---------------- small elementwise kernels ----------------
__global__ void bcast_q_kernel(const float* __restrict__ pos, float* __restrict__ out) {
  for (size_t i = (size_t)blockIdx.x * blockDim.x + threadIdx.x; i < (size_t)NQD;
       i += (size_t)gridDim.x * blockDim.x)
    out[i] = pos[i % QD];
}
__global__ void add_q_kernel(const float* __restrict__ prev, const float* __restrict__ pos,
                             float* __restrict__ x) {
  for (size_t i = (size_t)blockIdx.x * blockDim.x + threadIdx.x; i < (size_t)NQD;
       i += (size_t)gridDim.x * blockDim.x)
    x[i] = prev[i] + pos[i % QD];
}
__global__ void finalize_kernel(const float* __restrict__ lr5, float* __restrict__ det,
                                float* __restrict__ mask) {
  int i = blockIdx.x * blockDim.x + threadIdx.x;
  if (i < NQ * ODIM) det[i] = lr5[i];
  if (i < NQ) mask[i] = (lr5[(size_t)i * ODIM] >= 0.5f) ? 1.0f : 0.0f;
}

// ---------------- host ----------------
extern "C" void kernel_launch(void* const* d_in, const int* in_sizes, int n_in,
                              void* d_out, int out_size, void* d_ws, size_t ws_size,
                              hipStream_t stream) {
  const float* bev  = (const float*)d_in[0];
  const float* pos  = (const float*)d_in[1];
  const float* Wq   = (const float*)d_in[2];  const float* bq  = (const float*)d_in[3];
  const float* Wk   = (const float*)d_in[4];  const float* bk  = (const float*)d_in[5];
  const float* Wv   = (const float*)d_in[6];  const float* bv  = (const float*)d_in[7];
  const float* Wo   = (const float*)d_in[8];  const float* bo  = (const float*)d_in[9];
  const float* ln1g = (const float*)d_in[10]; const float* ln1b = (const float*)d_in[11];
  const float* ln2g = (const float*)d_in[12]; const float* ln2b = (const float*)d_in[13];
  const float* ln3g = (const float*)d_in[14]; const float* ln3b = (const float*)d_in[15];
  const float* dvW  = (const float*)d_in[16]; const float* dvb = (const float*)d_in[17];
  const float* offW = (const float*)d_in[18]; const float* offb = (const float*)d_in[19];
  const float* awW  = (const float*)d_in[20]; const float* awb = (const float*)d_in[21];
  const float* doW  = (const float*)d_in[22]; const float* dob = (const float*)d_in[23];
  const float* f1W  = (const float*)d_in[24]; const float* f1b = (const float*)d_in[25];
  const float* f2W  = (const float*)d_in[26]; const float* f2b = (const float*)d_in[27];
  const float* dW1  = (const float*)d_in[28]; const float* db1 = (const float*)d_in[29];
  const float* dW2  = (const float*)d_in[30]; const float* db2 = (const float*)d_in[31];

  // workspace: exactly 4*NQD floats (~29.5 MiB)
  float* w = (float*)d_ws;
  float* b0 = w + 0 * (size_t)NQD;   // x -> x3
  float* b1 = w + 1 * (size_t)NQD;   // q -> a -> d -> ffh(lo) -> deth
  float* b2 = w + 2 * (size_t)NQD;   // k -> x2 -> ffh(hi)
  float* b3 = w + 3 * (size_t)NQD;   // v -> dtmp -> f
  float* ffh = b1;                   // spans b1..b2 (NQ*FF contiguous)

  float* out_output = (float*)d_out;               // dual use: persistent `output` + mid-layer `o`
  float* out_det    = out_output + (size_t)NQD;
  float* out_mask   = out_det + (size_t)NQ * ODIM;
  float* out_lr     = out_mask + (size_t)NQ;

  const dim3 blk256(256);
  const dim3 gemmGridD((NQ + TM - 1) / TM, (D + TN - 1) / TN);
  const dim3 gemmGridFF((NQ + TM - 1) / TM, (FF + TN - 1) / TN);
  const dim3 gemmGrid1((NQ + TM - 1) / TM, 1);
  const dim3 attnGrid((Q + 255) / 256, NH, N);
  const dim3 lnGrid(NQ);
  const dim3 defGrid(NQ);
  const int ewGrid = 1024;

  // output_0 := queries (pos broadcast)
  bcast_q_kernel<<<ewGrid, blk256, 0, stream>>>(pos, out_output);

  for (int i = 0; i < L; ++i) {
    const size_t wDD = (size_t)i * D * D;
    // x = output + queries -> b0
    add_q_kernel<<<ewGrid, blk256, 0, stream>>>(out_output, pos, b0);
    // q,k,v
    gemm_kernel<0><<<gemmGridD, blk256, 0, stream>>>(b0, Wq + wDD, bq + (size_t)i * D, b1, NQ, D, D);
    gemm_kernel<0><<<gemmGridD, blk256, 0, stream>>>(b0, Wk + wDD, bk + (size_t)i * D, b2, NQ, D, D);
    gemm_kernel<0><<<gemmGridD, blk256, 0, stream>>>(b0, Wv + wDD, bv + (size_t)i * D, b3, NQ, D, D);
    // attention -> o (in out_output region)
    attn_kernel<<<attnGrid, blk256, 0, stream>>>(b1, b2, b3, out_output);
    // a = o @ Wo + bo -> b1
    gemm_kernel<0><<<gemmGridD, blk256, 0, stream>>>(out_output, Wo + wDD, bo + (size_t)i * D, b1, NQ, D, D);
    // x2 = LN1(x + a) -> b2
    ln_add_kernel<<<lnGrid, blk256, 0, stream>>>(b0, b1, ln1g + (size_t)i * D, ln1b + (size_t)i * D, b2);
    // deform (fused off/aw + gather + per-head projection) -> b3
    deform_kernel<<<defGrid, blk256, 0, stream>>>(bev, b2,
                                                  offW + (size_t)i * D * (NH * P * 2), offb + (size_t)i * (NH * P * 2),
                                                  awW + (size_t)i * D * (NH * P), awb + (size_t)i * (NH * P),
                                                  dvW + wDD, dvb + (size_t)i * D, b3);
    // d = dtmp @ do_W + do_b -> b1
    gemm_kernel<0><<<gemmGridD, blk256, 0, stream>>>(b3, doW + wDD, dob + (size_t)i * D, b1, NQ, D, D);
    // x3 = LN2(x2 + d) -> b0
    ln_add_kernel<<<lnGrid, blk256, 0, stream>>>(b2, b1, ln2g + (size_t)i * D, ln2b + (size_t)i * D, b0);
    // FFN: h = relu(x3@f1) -> ffh (b1..b2), f = h@f2 -> b3
    gemm_kernel<1><<<gemmGridFF, blk256, 0, stream>>>(b0, f1W + (size_t)i * D * FF, f1b + (size_t)i * FF, ffh, NQ, D, FF);
    gemm_kernel<0><<<gemmGridD, blk256, 0, stream>>>(ffh, f2W + (size_t)i * FF * D, f2b + (size_t)i * D, b3, NQ, FF, D);
    // output = LN3(x3 + f) -> out_output
    ln_add_kernel<<<lnGrid, blk256, 0, stream>>>(b0, b3, ln3g + (size_t)i * D, ln3b + (size_t)i * D, out_output);
    // det head -> layer_results[i]
    gemm_kernel<1><<<gemmGridD, blk256, 0, stream>>>(out_output, dW1, db1, b1, NQ, D, D);
    gemm_kernel<2><<<gemmGrid1, blk256, 0, stream>>>(b1, dW2, db2, out_lr + (size_t)i * NQ * ODIM, NQ, D, ODIM);
  }

  finalize_kernel<<<(NQ * ODIM + 255) / 256, blk256, 0, stream>>>(out_lr + (size_t)(L - 1) * NQ * ODIM,
                                                                  out_det, out_mask);
}

// Round 7
// 4678.641 us; speedup vs baseline: 1.0727x; 1.0727x over previous
//
#include <hip/hip_runtime.h>
#include <math.h>

#define N 8
#define Q 900
#define D 256
#define HB 200
#define WB 200
#define L 6
#define NH 8
#define P 4
#define HD 32
#define FF 512
#define NCLS 10
#define ODIM 18
#define HW (HB*WB)
#define NQ (N*Q)
#define NQD (NQ*D)
#define QD (Q*D)
#define SCALE 0.17677669529663687f

// ---------------- generic tiled f32 GEMM:  C[M,Nc] = act(A[M,K] @ B[K,Nc] + bias) ----------------
// ACT: 0 = none, 1 = relu, 2 = det head (sigmoid on cols < NCLS)
#define TM 64
#define TN 64
#define TK 16

template <int ACT>
__global__ __launch_bounds__(256) void gemm_kernel(
    const float* __restrict__ A, const float* __restrict__ B,
    const float* __restrict__ bias, float* __restrict__ C,
    int M, int K, int Nc) {
  __shared__ float AsT[TK][TM + 4];
  __shared__ float Bs[TK][TN + 4];
  const int tid = threadIdx.x;
  const int tx = tid & 15, ty = tid >> 4;
  const int m0 = blockIdx.x * TM, n0 = blockIdx.y * TN;

  float c[4][4] = {};

  for (int kt = 0; kt < K; kt += TK) {
    {
      int r = tid >> 2;                  // 0..63
      int cb = (tid & 3) * 4;            // 0,4,8,12
      int gr = m0 + r;
      float4 av = make_float4(0.f, 0.f, 0.f, 0.f);
      if (gr < M) av = *(const float4*)(A + (size_t)gr * K + kt + cb);
      AsT[cb + 0][r] = av.x;
      AsT[cb + 1][r] = av.y;
      AsT[cb + 2][r] = av.z;
      AsT[cb + 3][r] = av.w;
    }
    {
      int r = tid >> 4;                  // 0..15
      int cb = (tid & 15) * 4;           // 0..60
#pragma unroll
      for (int u = 0; u < 4; ++u) {
        int gc = n0 + cb + u;
        Bs[r][cb + u] = (gc < Nc) ? B[(size_t)(kt + r) * Nc + gc] : 0.f;
      }
    }
    __syncthreads();
#pragma unroll
    for (int kk = 0; kk < TK; ++kk) {
      float4 av = *(const float4*)&AsT[kk][ty * 4];
      float4 bv = *(const float4*)&Bs[kk][tx * 4];
      c[0][0] += av.x * bv.x; c[0][1] += av.x * bv.y; c[0][2] += av.x * bv.z; c[0][3] += av.x * bv.w;
      c[1][0] += av.y * bv.x; c[1][1] += av.y * bv.y; c[1][2] += av.y * bv.z; c[1][3] += av.y * bv.w;
      c[2][0] += av.z * bv.x; c[2][1] += av.z * bv.y; c[2][2] += av.z * bv.z; c[2][3] += av.z * bv.w;
      c[3][0] += av.w * bv.x; c[3][1] += av.w * bv.y; c[3][2] += av.w * bv.z; c[3][3] += av.w * bv.w;
    }
    __syncthreads();
  }

#pragma unroll
  for (int i = 0; i < 4; ++i) {
    int row = m0 + ty * 4 + i;
    if (row >= M) continue;
#pragma unroll
    for (int j = 0; j < 4; ++j) {
      int col = n0 + tx * 4 + j;
      if (col >= Nc) continue;
      float v = c[i][j] + bias[col];
      if (ACT == 1) v = fmaxf(v, 0.f);
      if (ACT == 2 && col < NCLS) v = 1.f / (1.f + expf(-v));
      C[(size_t)row * Nc + col] = v;
    }
  }
}

// ---------------- MHA: 4 lanes per query row (8 dims each), online softmax over 900 keys ----------------
__global__ __launch_bounds__(1024) void attn_kernel(
    const float* __restrict__ qg, const float* __restrict__ kg,
    const float* __restrict__ vg, float* __restrict__ og) {
  const int n = blockIdx.z, h = blockIdx.y;
  const int tid = threadIdx.x;
  const int wave = tid >> 6;              // 0..15
  const int lane = tid & 63;
  const int g = lane >> 4;                // dim-group 0..3 (8 dims each)
  const int rw = lane & 15;               // row within wave
  const int r = blockIdx.x * 256 + wave * 16 + rw;
  const bool active = (r < Q);

  __shared__ float ks[64][36];
  __shared__ float vs[64][36];

  float qreg[8];
  if (active) {
    const float* qp = qg + ((size_t)(n * Q + r) * D + h * HD + g * 8);
    float4 v0 = *(const float4*)qp;
    float4 v1 = *(const float4*)(qp + 4);
    qreg[0] = v0.x; qreg[1] = v0.y; qreg[2] = v0.z; qreg[3] = v0.w;
    qreg[4] = v1.x; qreg[5] = v1.y; qreg[6] = v1.z; qreg[7] = v1.w;
  }
  float m = -1e30f, l = 0.f;
  float acc[8] = {};

  for (int kt = 0; kt < Q; kt += 64) {
    int nk = min(64, Q - kt);
    {
      int row = tid >> 4;                 // 0..63
      int c2 = (tid & 15) * 2;            // 0,2,..,30
      if (kt + row < Q) {
        const float* kp = kg + ((size_t)(n * Q + kt + row) * D + h * HD + c2);
        const float* vp = vg + ((size_t)(n * Q + kt + row) * D + h * HD + c2);
        *(float2*)&ks[row][c2] = *(const float2*)kp;
        *(float2*)&vs[row][c2] = *(const float2*)vp;
      }
    }
    __syncthreads();
    if (active) {
      for (int j = 0; j < nk; ++j) {
        float s = 0.f;
#pragma unroll
        for (int d0 = 0; d0 < 8; ++d0) s += qreg[d0] * ks[j][g * 8 + d0];
        s += __shfl_xor(s, 16);
        s += __shfl_xor(s, 32);
        s *= SCALE;
        if (s > m) {
          float corr = expf(m - s);
          l *= corr;
#pragma unroll
          for (int d0 = 0; d0 < 8; ++d0) acc[d0] *= corr;
          m = s;
        }
        float p = expf(s - m);
        l += p;
#pragma unroll
        for (int d0 = 0; d0 < 8; ++d0) acc[d0] += p * vs[j][g * 8 + d0];
      }
    }
    __syncthreads();
  }
  if (active) {
    float inv = 1.f / l;
    float* op = og + ((size_t)(n * Q + r) * D + h * HD + g * 8);
#pragma unroll
    for (int d0 = 0; d0 < 8; ++d0) op[d0] = acc[d0] * inv;
  }
}

// ---------------- LayerNorm of (A + B): one wave per row, shuffle reductions, no barriers ----------------
__global__ __launch_bounds__(256) void ln_add_kernel(
    const float* __restrict__ A, const float* __restrict__ Bp,
    const float* __restrict__ g, const float* __restrict__ b,
    float* __restrict__ out) {
  const int wave = threadIdx.x >> 6;
  const int lane = threadIdx.x & 63;
  const int row = blockIdx.x * 4 + wave;
  const size_t base = (size_t)row * D + lane * 4;
  float4 a4 = *(const float4*)(A + base);
  float4 b4 = *(const float4*)(Bp + base);
  float v0 = a4.x + b4.x, v1 = a4.y + b4.y, v2 = a4.z + b4.z, v3 = a4.w + b4.w;
  float sum = v0 + v1 + v2 + v3;
#pragma unroll
  for (int off = 1; off < 64; off <<= 1) sum += __shfl_xor(sum, off);
  float mean = sum * (1.f / D);
  float d0 = v0 - mean, d1 = v1 - mean, d2 = v2 - mean, d3 = v3 - mean;
  float vsum = d0 * d0 + d1 * d1 + d2 * d2 + d3 * d3;
#pragma unroll
  for (int off = 1; off < 64; off <<= 1) vsum += __shfl_xor(vsum, off);
  float inv_std = 1.0f / sqrtf(vsum * (1.f / D) + 1e-5f);
  float4 g4 = *(const float4*)(g + lane * 4);
  float4 bb4 = *(const float4*)(b + lane * 4);
  float4 o4;
  o4.x = d0 * inv_std * g4.x + bb4.x;
  o4.y = d1 * inv_std * g4.y + bb4.y;
  o4.z = d2 * inv_std * g4.z + bb4.z;
  o4.w = d3 * inv_std * g4.w + bb4.w;
  *(float4*)(out + base) = o4;
}

// ---------------- deformable attention, fully fused (round-5 verified version) ----------------
__global__ __launch_bounds__(256) void deform_kernel(
    const float* __restrict__ bev, const float* __restrict__ x2,
    const float* __restrict__ offW, const float* __restrict__ offb,
    const float* __restrict__ awW, const float* __restrict__ awb,
    const float* __restrict__ dvW, const float* __restrict__ dvb,
    float* __restrict__ dtmp) {
  const int bq = blockIdx.x;  // n*Q + qi
  const int n = bq / Q, qi = bq - n * Q;
  const int t = threadIdx.x;

  __shared__ float x2s[D];
  __shared__ float logit_s[96];          // 64 off logits + 32 aw logits
  __shared__ float aw_s[NH * P];
  __shared__ int   idx_s[NH * P * 4];
  __shared__ float w_s[NH * P * 4];
  __shared__ float agg_s[NH][D + 4];

  x2s[t] = x2[(size_t)bq * D + t];
  __syncthreads();

  // ---- off / aw logits: 96 dot products of length 256 ----
  if (t < 96) {
    float acc;
    if (t < 64) {
      acc = offb[t];
      for (int dd = 0; dd < D; ++dd) acc += x2s[dd] * offW[(size_t)dd * 64 + t];
    } else {
      int j = t - 64;
      acc = awb[j];
      for (int dd = 0; dd < D; ++dd) acc += x2s[dd] * awW[(size_t)dd * 32 + j];
    }
    logit_s[t] = acc;
  }
  __syncthreads();

  // ---- corners & bilinear weights (t = h*P+p), aw softmax (t = h) ----
  if (t < NH * P) {
    // reference point: XLA f32 linspace, reciprocal-multiply delta
    float tq = __fmul_rn((float)qi, 44.492767333984375f);
    int ir = (int)rintf(tq);
    float rx = (float)(ir % WB);
    float ry = (float)(ir / WB);
    float ox = logit_s[t * 2 + 0];
    float oy = logit_s[t * 2 + 1];
    float lx = fminf(fmaxf(rx + ox, 0.f), (float)(WB - 1));
    float ly = fminf(fmaxf(ry + oy, 0.f), (float)(HB - 1));
    float x0 = floorf(lx), y0 = floorf(ly);
    float x1 = fminf(x0 + 1.f, (float)(WB - 1));
    float y1 = fminf(y0 + 1.f, (float)(HB - 1));
    float wx = lx - x0, wy = ly - y0;
    int b4 = t * 4;
    idx_s[b4 + 0] = (int)y0 * WB + (int)x0; w_s[b4 + 0] = (1.f - wx) * (1.f - wy);
    idx_s[b4 + 1] = (int)y0 * WB + (int)x1; w_s[b4 + 1] = wx * (1.f - wy);
    idx_s[b4 + 2] = (int)y1 * WB + (int)x0; w_s[b4 + 2] = (1.f - wx) * wy;
    idx_s[b4 + 3] = (int)y1 * WB + (int)x1; w_s[b4 + 3] = wx * wy;
  }
  if (t < NH) {
    float l0 = logit_s[64 + t * P + 0], l1 = logit_s[64 + t * P + 1];
    float l2 = logit_s[64 + t * P + 2], l3 = logit_s[64 + t * P + 3];
    float mx = fmaxf(fmaxf(l0, l1), fmaxf(l2, l3));
    float e0 = expf(l0 - mx), e1 = expf(l1 - mx), e2 = expf(l2 - mx), e3 = expf(l3 - mx);
    float inv = 1.f / (e0 + e1 + e2 + e3);
    aw_s[t * P + 0] = e0 * inv; aw_s[t * P + 1] = e1 * inv;
    aw_s[t * P + 2] = e2 * inv; aw_s[t * P + 3] = e3 * inv;
  }
  __syncthreads();

  // ---- gather + blend: wave-pair handles heads {w, w+4}; lane handles 4 channels ----
  {
    const float* bevn = bev + (size_t)n * HW * D;
    const int w4 = t >> 6;        // 0..3
    const int lane = t & 63;      // 0..63
#pragma unroll
    for (int hh2 = 0; hh2 < 2; ++hh2) {
      const int h = w4 + hh2 * 4;
#pragma unroll
      for (int cc = 0; cc < 4; ++cc) {
        const int c = lane + cc * 64;
        float acc = 0.f;
#pragma unroll
        for (int p = 0; p < P; ++p) {
          const int e = h * P + p;
          const int b4 = e * 4;
          float s4 = w_s[b4 + 0] * bevn[(size_t)idx_s[b4 + 0] * D + c]
                   + w_s[b4 + 1] * bevn[(size_t)idx_s[b4 + 1] * D + c]
                   + w_s[b4 + 2] * bevn[(size_t)idx_s[b4 + 2] * D + c]
                   + w_s[b4 + 3] * bevn[(size_t)idx_s[b4 + 3] * D + c];
          acc += aw_s[e] * s4;
        }
        agg_s[h][c] = acc;
      }
    }
  }
  __syncthreads();

  // ---- per-head projection: out channel t = head t>>5 ----
  {
    const int h = t >> 5;
    float acc = dvb[t];
    const float* wcol = dvW + t;
    const float* ag = agg_s[h];
    for (int dd = 0; dd < D; ++dd) acc += ag[dd] * wcol[(size_t)dd * D];
    dtmp[(size_t)bq * D + t] = acc;
  }
}

// ---------------- small elementwise kernels ----------------
__global__ void bcast_q_kernel(const float* __restrict__ pos, float* __restrict__ out) {
  for (size_t i = (size_t)blockIdx.x * blockDim.x + threadIdx.x; i < (size_t)NQD;
       i += (size_t)gridDim.x * blockDim.x)
    out[i] = pos[i % QD];
}
__global__ void add_q_kernel(const float* __restrict__ prev, const float* __restrict__ pos,
                             float* __restrict__ x) {
  for (size_t i = (size_t)blockIdx.x * blockDim.x + threadIdx.x; i < (size_t)NQD;
       i += (size_t)gridDim.x * blockDim.x)
    x[i] = prev[i] + pos[i % QD];
}
__global__ void finalize_kernel(const float* __restrict__ lr5, float* __restrict__ det,
                                float* __restrict__ mask) {
  int i = blockIdx.x * blockDim.x + threadIdx.x;
  if (i < NQ * ODIM) det[i] = lr5[i];
  if (i < NQ) mask[i] = (lr5[(size_t)i * ODIM] >= 0.5f) ? 1.0f : 0.0f;
}

// ---------------- host ----------------
extern "C" void kernel_launch(void* const* d_in, const int* in_sizes, int n_in,
                              void* d_out, int out_size, void* d_ws, size_t ws_size,
                              hipStream_t stream) {
  const float* bev  = (const float*)d_in[0];
  const float* pos  = (const float*)d_in[1];
  const float* Wq   = (const float*)d_in[2];  const float* bq  = (const float*)d_in[3];
  const float* Wk   = (const float*)d_in[4];  const float* bk  = (const float*)d_in[5];
  const float* Wv   = (const float*)d_in[6];  const float* bv  = (const float*)d_in[7];
  const float* Wo   = (const float*)d_in[8];  const float* bo  = (const float*)d_in[9];
  const float* ln1g = (const float*)d_in[10]; const float* ln1b = (const float*)d_in[11];
  const float* ln2g = (const float*)d_in[12]; const float* ln2b = (const float*)d_in[13];
  const float* ln3g = (const float*)d_in[14]; const float* ln3b = (const float*)d_in[15];
  const float* dvW  = (const float*)d_in[16]; const float* dvb = (const float*)d_in[17];
  const float* offW = (const float*)d_in[18]; const float* offb = (const float*)d_in[19];
  const float* awW  = (const float*)d_in[20]; const float* awb = (const float*)d_in[21];
  const float* doW  = (const float*)d_in[22]; const float* dob = (const float*)d_in[23];
  const float* f1W  = (const float*)d_in[24]; const float* f1b = (const float*)d_in[25];
  const float* f2W  = (const float*)d_in[26]; const float* f2b = (const float*)d_in[27];
  const float* dW1  = (const float*)d_in[28]; const float* db1 = (const float*)d_in[29];
  const float* dW2  = (const float*)d_in[30]; const float* db2 = (const float*)d_in[31];

  // workspace: exactly 4*NQD floats (~29.5 MiB)
  float* w = (float*)d_ws;
  float* b0 = w + 0 * (size_t)NQD;   // x -> x3
  float* b1 = w + 1 * (size_t)NQD;   // q -> a -> d -> ffh(lo) -> deth
  float* b2 = w + 2 * (size_t)NQD;   // k -> x2 -> ffh(hi)
  float* b3 = w + 3 * (size_t)NQD;   // v -> dtmp -> f
  float* ffh = b1;                   // spans b1..b2 (NQ*FF contiguous)

  float* out_output = (float*)d_out;               // dual use: persistent `output` + mid-layer `o`
  float* out_det    = out_output + (size_t)NQD;
  float* out_mask   = out_det + (size_t)NQ * ODIM;
  float* out_lr     = out_mask + (size_t)NQ;

  const dim3 blk256(256);
  const dim3 blk1024(1024);
  const dim3 gemmGridD((NQ + TM - 1) / TM, (D + TN - 1) / TN);
  const dim3 gemmGridFF((NQ + TM - 1) / TM, (FF + TN - 1) / TN);
  const dim3 gemmGrid1((NQ + TM - 1) / TM, 1);
  const dim3 attnGrid((Q + 255) / 256, NH, N);
  const dim3 lnGrid(NQ / 4);
  const dim3 defGrid(NQ);
  const int ewGrid = 1024;

  // output_0 := queries (pos broadcast)
  bcast_q_kernel<<<ewGrid, blk256, 0, stream>>>(pos, out_output);

  for (int i = 0; i < L; ++i) {
    const size_t wDD = (size_t)i * D * D;
    // x = output + queries -> b0
    add_q_kernel<<<ewGrid, blk256, 0, stream>>>(out_output, pos, b0);
    // q,k,v
    gemm_kernel<0><<<gemmGridD, blk256, 0, stream>>>(b0, Wq + wDD, bq + (size_t)i * D, b1, NQ, D, D);
    gemm_kernel<0><<<gemmGridD, blk256, 0, stream>>>(b0, Wk + wDD, bk + (size_t)i * D, b2, NQ, D, D);
    gemm_kernel<0><<<gemmGridD, blk256, 0, stream>>>(b0, Wv + wDD, bv + (size_t)i * D, b3, NQ, D, D);
    // attention -> o (in out_output region)
    attn_kernel<<<attnGrid, blk1024, 0, stream>>>(b1, b2, b3, out_output);
    // a = o @ Wo + bo -> b1
    gemm_kernel<0><<<gemmGridD, blk256, 0, stream>>>(out_output, Wo + wDD, bo + (size_t)i * D, b1, NQ, D, D);
    // x2 = LN1(x + a) -> b2
    ln_add_kernel<<<lnGrid, blk256, 0, stream>>>(b0, b1, ln1g + (size_t)i * D, ln1b + (size_t)i * D, b2);
    // deform (fused off/aw + gather + per-head projection) -> b3
    deform_kernel<<<defGrid, blk256, 0, stream>>>(bev, b2,
                                                  offW + (size_t)i * D * (NH * P * 2), offb + (size_t)i * (NH * P * 2),
                                                  awW + (size_t)i * D * (NH * P), awb + (size_t)i * (NH * P),
                                                  dvW + wDD, dvb + (size_t)i * D, b3);
    // d = dtmp @ do_W + do_b -> b1
    gemm_kernel<0><<<gemmGridD, blk256, 0, stream>>>(b3, doW + wDD, dob + (size_t)i * D, b1, NQ, D, D);
    // x3 = LN2(x2 + d) -> b0
    ln_add_kernel<<<lnGrid, blk256, 0, stream>>>(b2, b1, ln2g + (size_t)i * D, ln2b + (size_t)i * D, b0);
    // FFN: h = relu(x3@f1) -> ffh (b1..b2), f = h@f2 -> b3
    gemm_kernel<1><<<gemmGridFF, blk256, 0, stream>>>(b0, f1W + (size_t)i * D * FF, f1b + (size_t)i * FF, ffh, NQ, D, FF);
    gemm_kernel<0><<<gemmGridD, blk256, 0, stream>>>(ffh, f2W + (size_t)i * FF * D, f2b + (size_t)i * D, b3, NQ, FF, D);
    // output = LN3(x3 + f) -> out_output
    ln_add_kernel<<<lnGrid, blk256, 0, stream>>>(b0, b3, ln3g + (size_t)i * D, ln3b + (size_t)i * D, out_output);
    // det head -> layer_results[i]
    gemm_kernel<1><<<gemmGridD, blk256, 0, stream>>>(out_output, dW1, db1, b1, NQ, D, D);
    gemm_kernel<2><<<gemmGrid1, blk256, 0, stream>>>(b1, dW2, db2, out_lr + (size_t)i * NQ * ODIM, NQ, D, ODIM);
  }

  finalize_kernel<<<(NQ * ODIM + 255) / 256, blk256, 0, stream>>>(out_lr + (size_t)(L - 1) * NQ * ODIM,
                                                                  out_det, out_mask);
}

// Round 8
// 3827.927 us; speedup vs baseline: 1.3111x; 1.2222x over previous
//
#include <hip/hip_runtime.h>
#include <hip/hip_bf16.h>
#include <math.h>

#define N 8
#define Q 900
#define D 256
#define HB 200
#define WB 200
#define L 6
#define NH 8
#define P 4
#define HD 32
#define FF 512
#define NCLS 10
#define ODIM 18
#define HW (HB*WB)
#define NQ (N*Q)
#define NQD (NQ*D)
#define QD (Q*D)
#define SCALE 0.17677669529663687f

typedef __attribute__((ext_vector_type(4))) float f32x4;
typedef __attribute__((ext_vector_type(8))) short short8v;

__device__ __forceinline__ short bf16_of(float f) {
  __hip_bfloat16 h = __float2bfloat16(f);
  return __builtin_bit_cast(short, h);
}

// ---------------- generic tiled f32 GEMM:  C[M,Nc] = act(A[M,K] @ B[K,Nc] + bias) ----------------
// ACT: 0 = none, 1 = relu, 2 = det head (sigmoid on cols < NCLS)
#define TM 64
#define TN 64
#define TK 16

template <int ACT>
__global__ __launch_bounds__(256) void gemm_kernel(
    const float* __restrict__ A, const float* __restrict__ B,
    const float* __restrict__ bias, float* __restrict__ C,
    int M, int K, int Nc) {
  __shared__ float AsT[TK][TM + 4];
  __shared__ float Bs[TK][TN + 4];
  const int tid = threadIdx.x;
  const int tx = tid & 15, ty = tid >> 4;
  const int m0 = blockIdx.x * TM, n0 = blockIdx.y * TN;

  float c[4][4] = {};

  for (int kt = 0; kt < K; kt += TK) {
    {
      int r = tid >> 2;                  // 0..63
      int cb = (tid & 3) * 4;            // 0,4,8,12
      int gr = m0 + r;
      float4 av = make_float4(0.f, 0.f, 0.f, 0.f);
      if (gr < M) av = *(const float4*)(A + (size_t)gr * K + kt + cb);
      AsT[cb + 0][r] = av.x;
      AsT[cb + 1][r] = av.y;
      AsT[cb + 2][r] = av.z;
      AsT[cb + 3][r] = av.w;
    }
    {
      int r = tid >> 4;                  // 0..15
      int cb = (tid & 15) * 4;           // 0..60
#pragma unroll
      for (int u = 0; u < 4; ++u) {
        int gc = n0 + cb + u;
        Bs[r][cb + u] = (gc < Nc) ? B[(size_t)(kt + r) * Nc + gc] : 0.f;
      }
    }
    __syncthreads();
#pragma unroll
    for (int kk = 0; kk < TK; ++kk) {
      float4 av = *(const float4*)&AsT[kk][ty * 4];
      float4 bv = *(const float4*)&Bs[kk][tx * 4];
      c[0][0] += av.x * bv.x; c[0][1] += av.x * bv.y; c[0][2] += av.x * bv.z; c[0][3] += av.x * bv.w;
      c[1][0] += av.y * bv.x; c[1][1] += av.y * bv.y; c[1][2] += av.y * bv.z; c[1][3] += av.y * bv.w;
      c[2][0] += av.z * bv.x; c[2][1] += av.z * bv.y; c[2][2] += av.z * bv.z; c[2][3] += av.z * bv.w;
      c[3][0] += av.w * bv.x; c[3][1] += av.w * bv.y; c[3][2] += av.w * bv.z; c[3][3] += av.w * bv.w;
    }
    __syncthreads();
  }

#pragma unroll
  for (int i = 0; i < 4; ++i) {
    int row = m0 + ty * 4 + i;
    if (row >= M) continue;
#pragma unroll
    for (int j = 0; j < 4; ++j) {
      int col = n0 + tx * 4 + j;
      if (col >= Nc) continue;
      float v = c[i][j] + bias[col];
      if (ACT == 1) v = fmaxf(v, 0.f);
      if (ACT == 2 && col < NCLS) v = 1.f / (1.f + expf(-v));
      C[(size_t)row * Nc + col] = v;
    }
  }
}

// ---------------- MHA: MFMA flash attention (bf16 inputs, f32 accumulate) ----------------
// Block = 4 waves; wave handles 16 q-rows of one (n,h). Swapped QK^T so each lane's
// 16 scores belong to one q-row (col=lane&15). k-slot permutation cancels because
// A/B frags are packed by identical code.
__global__ __launch_bounds__(256) void attn_kernel(
    const float* __restrict__ qg, const float* __restrict__ kg,
    const float* __restrict__ vg, float* __restrict__ og) {
  const int n = blockIdx.z, h = blockIdx.y;
  const int wv = threadIdx.x >> 6;
  const int lane = threadIdx.x & 63;
  const int g = lane >> 4;          // 0..3
  const int c = lane & 15;          // q (for scores) / d (for output)
  const int q0 = blockIdx.x * 64 + wv * 16;

  const float* qb = qg + (size_t)n * Q * D + h * HD;
  const float* kb = kg + (size_t)n * Q * D + h * HD;
  const float* vb = vg + (size_t)n * Q * D + h * HD;

  // Q B-frag: row q0+c, dims g*8 .. g*8+7
  short8v qf = {};
  {
    int qr = q0 + c;
    if (qr < Q) {
      const float* qp = qb + (size_t)qr * D + g * 8;
#pragma unroll
      for (int j = 0; j < 8; ++j) qf[j] = bf16_of(qp[j]);
    }
  }

  const float SC2 = SCALE * 1.4426950408889634f;   // into exp2 domain
  float m2 = -1e30f, l = 0.f;
  f32x4 acc0 = {0.f, 0.f, 0.f, 0.f}, acc1 = {0.f, 0.f, 0.f, 0.f};

  for (int kt0 = 0; kt0 < Q; kt0 += 64) {
    float s[16];
    // QK^T: 4 key-tiles of 16; lane gets scores for q=c, keys kt0 + t*16 + g*4 + r
#pragma unroll
    for (int t = 0; t < 4; ++t) {
      short8v kf = {};
      int kr = kt0 + t * 16 + c;
      if (kr < Q) {
        const float* kp = kb + (size_t)kr * D + g * 8;
#pragma unroll
        for (int j = 0; j < 8; ++j) kf[j] = bf16_of(kp[j]);
      }
      f32x4 d = __builtin_amdgcn_mfma_f32_16x16x32_bf16(kf, qf, (f32x4){0.f, 0.f, 0.f, 0.f}, 0, 0, 0);
#pragma unroll
      for (int r = 0; r < 4; ++r) s[t * 4 + r] = d[r];
    }
    // scale into exp2 domain + mask OOB keys
#pragma unroll
    for (int t = 0; t < 4; ++t)
#pragma unroll
      for (int r = 0; r < 4; ++r) {
        int key = kt0 + t * 16 + g * 4 + r;
        s[t * 4 + r] = (key < Q) ? s[t * 4 + r] * SC2 : -1e30f;
      }
    // row max (in-lane 16, then across the 4 lane-copies)
    float tm = s[0];
#pragma unroll
    for (int j = 1; j < 16; ++j) tm = fmaxf(tm, s[j]);
    tm = fmaxf(tm, __shfl_xor(tm, 16));
    tm = fmaxf(tm, __shfl_xor(tm, 32));
    float m2n = fmaxf(m2, tm);
    float corr = exp2f(m2 - m2n);    // first tile: exp2(-inf) = 0
    m2 = m2n;
    // p = exp2(s - m), row sum
    float ps = 0.f;
#pragma unroll
    for (int j = 0; j < 16; ++j) { s[j] = exp2f(s[j] - m2); ps += s[j]; }
    ps += __shfl_xor(ps, 16);
    ps += __shfl_xor(ps, 32);
    l = l * corr + ps;
    // rescale accumulators (acc row = q = g*4+r; corr lives at lane q)
    float cr0 = __shfl(corr, g * 4 + 0);
    float cr1 = __shfl(corr, g * 4 + 1);
    float cr2 = __shfl(corr, g * 4 + 2);
    float cr3 = __shfl(corr, g * 4 + 3);
    acc0[0] *= cr0; acc0[1] *= cr1; acc0[2] *= cr2; acc0[3] *= cr3;
    acc1[0] *= cr0; acc1[1] *= cr1; acc1[2] *= cr2; acc1[3] *= cr3;

    // PV: two 32-key pairs; A = P (rows=q, slots j -> key (pr*2+(j>>2))*16 + g*4 + (j&3)),
    // B = V with the SAME slot->key map (permutation cancels), cols = d (c, c+16).
#pragma unroll
    for (int pr = 0; pr < 2; ++pr) {
      short8v pa, v0 = {}, v1 = {};
#pragma unroll
      for (int j = 0; j < 8; ++j) pa[j] = bf16_of(s[pr * 8 + j]);
#pragma unroll
      for (int j = 0; j < 8; ++j) {
        int key = kt0 + (pr * 2 + (j >> 2)) * 16 + g * 4 + (j & 3);
        if (key < Q) {
          const float* vp = vb + (size_t)key * D;
          v0[j] = bf16_of(vp[c]);
          v1[j] = bf16_of(vp[c + 16]);
        }
      }
      acc0 = __builtin_amdgcn_mfma_f32_16x16x32_bf16(pa, v0, acc0, 0, 0, 0);
      acc1 = __builtin_amdgcn_mfma_f32_16x16x32_bf16(pa, v1, acc1, 0, 0, 0);
    }
  }

  // normalize and store: acc row r -> q = q0 + g*4 + r, cols d = c / c+16
  float inv = 1.f / l;
  float iv[4];
#pragma unroll
  for (int r = 0; r < 4; ++r) iv[r] = __shfl(inv, g * 4 + r);
#pragma unroll
  for (int r = 0; r < 4; ++r) {
    int qr = q0 + g * 4 + r;
    if (qr < Q) {
      float* op = og + (size_t)(n * Q + qr) * D + h * HD;
      op[c] = acc0[r] * iv[r];
      op[c + 16] = acc1[r] * iv[r];
    }
  }
}

// ---------------- LayerNorm of (A + B): one wave per row, shuffle reductions, no barriers ----------------
__global__ __launch_bounds__(256) void ln_add_kernel(
    const float* __restrict__ A, const float* __restrict__ Bp,
    const float* __restrict__ g, const float* __restrict__ b,
    float* __restrict__ out) {
  const int wave = threadIdx.x >> 6;
  const int lane = threadIdx.x & 63;
  const int row = blockIdx.x * 4 + wave;
  const size_t base = (size_t)row * D + lane * 4;
  float4 a4 = *(const float4*)(A + base);
  float4 b4 = *(const float4*)(Bp + base);
  float v0 = a4.x + b4.x, v1 = a4.y + b4.y, v2 = a4.z + b4.z, v3 = a4.w + b4.w;
  float sum = v0 + v1 + v2 + v3;
#pragma unroll
  for (int off = 1; off < 64; off <<= 1) sum += __shfl_xor(sum, off);
  float mean = sum * (1.f / D);
  float d0 = v0 - mean, d1 = v1 - mean, d2 = v2 - mean, d3 = v3 - mean;
  float vsum = d0 * d0 + d1 * d1 + d2 * d2 + d3 * d3;
#pragma unroll
  for (int off = 1; off < 64; off <<= 1) vsum += __shfl_xor(vsum, off);
  float inv_std = 1.0f / sqrtf(vsum * (1.f / D) + 1e-5f);
  float4 g4 = *(const float4*)(g + lane * 4);
  float4 bb4 = *(const float4*)(b + lane * 4);
  float4 o4;
  o4.x = d0 * inv_std * g4.x + bb4.x;
  o4.y = d1 * inv_std * g4.y + bb4.y;
  o4.z = d2 * inv_std * g4.z + bb4.z;
  o4.w = d3 * inv_std * g4.w + bb4.w;
  *(float4*)(out + base) = o4;
}

// ---------------- deformable attention, fully fused (verified) ----------------
__global__ __launch_bounds__(256) void deform_kernel(
    const float* __restrict__ bev, const float* __restrict__ x2,
    const float* __restrict__ offW, const float* __restrict__ offb,
    const float* __restrict__ awW, const float* __restrict__ awb,
    const float* __restrict__ dvW, const float* __restrict__ dvb,
    float* __restrict__ dtmp) {
  const int bq = blockIdx.x;  // n*Q + qi
  const int n = bq / Q, qi = bq - n * Q;
  const int t = threadIdx.x;

  __shared__ float x2s[D];
  __shared__ float logit_s[96];          // 64 off logits + 32 aw logits
  __shared__ float aw_s[NH * P];
  __shared__ int   idx_s[NH * P * 4];
  __shared__ float w_s[NH * P * 4];
  __shared__ float agg_s[NH][D + 4];

  x2s[t] = x2[(size_t)bq * D + t];
  __syncthreads();

  if (t < 96) {
    float acc;
    if (t < 64) {
      acc = offb[t];
      for (int dd = 0; dd < D; ++dd) acc += x2s[dd] * offW[(size_t)dd * 64 + t];
    } else {
      int j = t - 64;
      acc = awb[j];
      for (int dd = 0; dd < D; ++dd) acc += x2s[dd] * awW[(size_t)dd * 32 + j];
    }
    logit_s[t] = acc;
  }
  __syncthreads();

  if (t < NH * P) {
    // reference point: XLA f32 linspace, reciprocal-multiply delta
    float tq = __fmul_rn((float)qi, 44.492767333984375f);
    int ir = (int)rintf(tq);
    float rx = (float)(ir % WB);
    float ry = (float)(ir / WB);
    float ox = logit_s[t * 2 + 0];
    float oy = logit_s[t * 2 + 1];
    float lx = fminf(fmaxf(rx + ox, 0.f), (float)(WB - 1));
    float ly = fminf(fmaxf(ry + oy, 0.f), (float)(HB - 1));
    float x0 = floorf(lx), y0 = floorf(ly);
    float x1 = fminf(x0 + 1.f, (float)(WB - 1));
    float y1 = fminf(y0 + 1.f, (float)(HB - 1));
    float wx = lx - x0, wy = ly - y0;
    int b4 = t * 4;
    idx_s[b4 + 0] = (int)y0 * WB + (int)x0; w_s[b4 + 0] = (1.f - wx) * (1.f - wy);
    idx_s[b4 + 1] = (int)y0 * WB + (int)x1; w_s[b4 + 1] = wx * (1.f - wy);
    idx_s[b4 + 2] = (int)y1 * WB + (int)x0; w_s[b4 + 2] = (1.f - wx) * wy;
    idx_s[b4 + 3] = (int)y1 * WB + (int)x1; w_s[b4 + 3] = wx * wy;
  }
  if (t < NH) {
    float l0 = logit_s[64 + t * P + 0], l1 = logit_s[64 + t * P + 1];
    float l2 = logit_s[64 + t * P + 2], l3 = logit_s[64 + t * P + 3];
    float mx = fmaxf(fmaxf(l0, l1), fmaxf(l2, l3));
    float e0 = expf(l0 - mx), e1 = expf(l1 - mx), e2 = expf(l2 - mx), e3 = expf(l3 - mx);
    float inv = 1.f / (e0 + e1 + e2 + e3);
    aw_s[t * P + 0] = e0 * inv; aw_s[t * P + 1] = e1 * inv;
    aw_s[t * P + 2] = e2 * inv; aw_s[t * P + 3] = e3 * inv;
  }
  __syncthreads();

  {
    const float* bevn = bev + (size_t)n * HW * D;
    const int w4 = t >> 6;        // 0..3
    const int lane = t & 63;      // 0..63
#pragma unroll
    for (int hh2 = 0; hh2 < 2; ++hh2) {
      const int h = w4 + hh2 * 4;
#pragma unroll
      for (int cc = 0; cc < 4; ++cc) {
        const int c = lane + cc * 64;
        float acc = 0.f;
#pragma unroll
        for (int p = 0; p < P; ++p) {
          const int e = h * P + p;
          const int b4 = e * 4;
          float s4 = w_s[b4 + 0] * bevn[(size_t)idx_s[b4 + 0] * D + c]
                   + w_s[b4 + 1] * bevn[(size_t)idx_s[b4 + 1] * D + c]
                   + w_s[b4 + 2] * bevn[(size_t)idx_s[b4 + 2] * D + c]
                   + w_s[b4 + 3] * bevn[(size_t)idx_s[b4 + 3] * D + c];
          acc += aw_s[e] * s4;
        }
        agg_s[h][c] = acc;
      }
    }
  }
  __syncthreads();

  {
    const int h = t >> 5;
    float acc = dvb[t];
    const float* wcol = dvW + t;
    const float* ag = agg_s[h];
    for (int dd = 0; dd < D; ++dd) acc += ag[dd] * wcol[(size_t)dd * D];
    dtmp[(size_t)bq * D + t] = acc;
  }
}

// ---------------- small elementwise kernels ----------------
__global__ void bcast_q_kernel(const float* __restrict__ pos, float* __restrict__ out) {
  for (size_t i = (size_t)blockIdx.x * blockDim.x + threadIdx.x; i < (size_t)NQD;
       i += (size_t)gridDim.x * blockDim.x)
    out[i] = pos[i % QD];
}
__global__ void add_q_kernel(const float* __restrict__ prev, const float* __restrict__ pos,
                             float* __restrict__ x) {
  for (size_t i = (size_t)blockIdx.x * blockDim.x + threadIdx.x; i < (size_t)NQD;
       i += (size_t)gridDim.x * blockDim.x)
    x[i] = prev[i] + pos[i % QD];
}
__global__ void finalize_kernel(const float* __restrict__ lr5, float* __restrict__ det,
                                float* __restrict__ mask) {
  int i = blockIdx.x * blockDim.x + threadIdx.x;
  if (i < NQ * ODIM) det[i] = lr5[i];
  if (i < NQ) mask[i] = (lr5[(size_t)i * ODIM] >= 0.5f) ? 1.0f : 0.0f;
}

// ---------------- host ----------------
extern "C" void kernel_launch(void* const* d_in, const int* in_sizes, int n_in,
                              void* d_out, int out_size, void* d_ws, size_t ws_size,
                              hipStream_t stream) {
  const float* bev  = (const float*)d_in[0];
  const float* pos  = (const float*)d_in[1];
  const float* Wq   = (const float*)d_in[2];  const float* bq  = (const float*)d_in[3];
  const float* Wk   = (const float*)d_in[4];  const float* bk  = (const float*)d_in[5];
  const float* Wv   = (const float*)d_in[6];  const float* bv  = (const float*)d_in[7];
  const float* Wo   = (const float*)d_in[8];  const float* bo  = (const float*)d_in[9];
  const float* ln1g = (const float*)d_in[10]; const float* ln1b = (const float*)d_in[11];
  const float* ln2g = (const float*)d_in[12]; const float* ln2b = (const float*)d_in[13];
  const float* ln3g = (const float*)d_in[14]; const float* ln3b = (const float*)d_in[15];
  const float* dvW  = (const float*)d_in[16]; const float* dvb = (const float*)d_in[17];
  const float* offW = (const float*)d_in[18]; const float* offb = (const float*)d_in[19];
  const float* awW  = (const float*)d_in[20]; const float* awb = (const float*)d_in[21];
  const float* doW  = (const float*)d_in[22]; const float* dob = (const float*)d_in[23];
  const float* f1W  = (const float*)d_in[24]; const float* f1b = (const float*)d_in[25];
  const float* f2W  = (const float*)d_in[26]; const float* f2b = (const float*)d_in[27];
  const float* dW1  = (const float*)d_in[28]; const float* db1 = (const float*)d_in[29];
  const float* dW2  = (const float*)d_in[30]; const float* db2 = (const float*)d_in[31];

  // workspace: exactly 4*NQD floats (~29.5 MiB)
  float* w = (float*)d_ws;
  float* b0 = w + 0 * (size_t)NQD;   // x -> x3
  float* b1 = w + 1 * (size_t)NQD;   // q -> a -> d -> ffh(lo) -> deth
  float* b2 = w + 2 * (size_t)NQD;   // k -> x2 -> ffh(hi)
  float* b3 = w + 3 * (size_t)NQD;   // v -> dtmp -> f
  float* ffh = b1;                   // spans b1..b2 (NQ*FF contiguous)

  float* out_output = (float*)d_out;               // dual use: persistent `output` + mid-layer `o`
  float* out_det    = out_output + (size_t)NQD;
  float* out_mask   = out_det + (size_t)NQ * ODIM;
  float* out_lr     = out_mask + (size_t)NQ;

  const dim3 blk256(256);
  const dim3 gemmGridD((NQ + TM - 1) / TM, (D + TN - 1) / TN);
  const dim3 gemmGridFF((NQ + TM - 1) / TM, (FF + TN - 1) / TN);
  const dim3 gemmGrid1((NQ + TM - 1) / TM, 1);
  const dim3 attnGrid((Q + 63) / 64, NH, N);
  const dim3 lnGrid(NQ / 4);
  const dim3 defGrid(NQ);
  const int ewGrid = 1024;

  // output_0 := queries (pos broadcast)
  bcast_q_kernel<<<ewGrid, blk256, 0, stream>>>(pos, out_output);

  for (int i = 0; i < L; ++i) {
    const size_t wDD = (size_t)i * D * D;
    // x = output + queries -> b0
    add_q_kernel<<<ewGrid, blk256, 0, stream>>>(out_output, pos, b0);
    // q,k,v
    gemm_kernel<0><<<gemmGridD, blk256, 0, stream>>>(b0, Wq + wDD, bq + (size_t)i * D, b1, NQ, D, D);
    gemm_kernel<0><<<gemmGridD, blk256, 0, stream>>>(b0, Wk + wDD, bk + (size_t)i * D, b2, NQ, D, D);
    gemm_kernel<0><<<gemmGridD, blk256, 0, stream>>>(b0, Wv + wDD, bv + (size_t)i * D, b3, NQ, D, D);
    // attention -> o (in out_output region)
    attn_kernel<<<attnGrid, blk256, 0, stream>>>(b1, b2, b3, out_output);
    // a = o @ Wo + bo -> b1
    gemm_kernel<0><<<gemmGridD, blk256, 0, stream>>>(out_output, Wo + wDD, bo + (size_t)i * D, b1, NQ, D, D);
    // x2 = LN1(x + a) -> b2
    ln_add_kernel<<<lnGrid, blk256, 0, stream>>>(b0, b1, ln1g + (size_t)i * D, ln1b + (size_t)i * D, b2);
    // deform (fused off/aw + gather + per-head projection) -> b3
    deform_kernel<<<defGrid, blk256, 0, stream>>>(bev, b2,
                                                  offW + (size_t)i * D * (NH * P * 2), offb + (size_t)i * (NH * P * 2),
                                                  awW + (size_t)i * D * (NH * P), awb + (size_t)i * (NH * P),
                                                  dvW + wDD, dvb + (size_t)i * D, b3);
    // d = dtmp @ do_W + do_b -> b1
    gemm_kernel<0><<<gemmGridD, blk256, 0, stream>>>(b3, doW + wDD, dob + (size_t)i * D, b1, NQ, D, D);
    // x3 = LN2(x2 + d) -> b0
    ln_add_kernel<<<lnGrid, blk256, 0, stream>>>(b2, b1, ln2g + (size_t)i * D, ln2b + (size_t)i * D, b0);
    // FFN: h = relu(x3@f1) -> ffh (b1..b2), f = h@f2 -> b3
    gemm_kernel<1><<<gemmGridFF, blk256, 0, stream>>>(b0, f1W + (size_t)i * D * FF, f1b + (size_t)i * FF, ffh, NQ, D, FF);
    gemm_kernel<0><<<gemmGridD, blk256, 0, stream>>>(ffh, f2W + (size_t)i * FF * D, f2b + (size_t)i * D, b3, NQ, FF, D);
    // output = LN3(x3 + f) -> out_output
    ln_add_kernel<<<lnGrid, blk256, 0, stream>>>(b0, b3, ln3g + (size_t)i * D, ln3b + (size_t)i * D, out_output);
    // det head -> layer_results[i]
    gemm_kernel<1><<<gemmGridD, blk256, 0, stream>>>(out_output, dW1, db1, b1, NQ, D, D);
    gemm_kernel<2><<<gemmGrid1, blk256, 0, stream>>>(b1, dW2, db2, out_lr + (size_t)i * NQ * ODIM, NQ, D, ODIM);
  }

  finalize_kernel<<<(NQ * ODIM + 255) / 256, blk256, 0, stream>>>(out_lr + (size_t)(L - 1) * NQ * ODIM,
                                                                  out_det, out_mask);
}